// Round 1
// baseline (260.189 us; speedup 1.0000x reference)
//
#include <hip/hip_runtime.h>
#include <hip/hip_bf16.h>

#define IN_CAPS 64
#define IN_DIM 768
#define NUM_CAPS 4
#define DIM_CAPS 192
#define NDCOLS (NUM_CAPS * DIM_CAPS)   // 768
#define EPSF 1e-8f

// ---------- helpers ----------
__device__ __forceinline__ float wave_sum(float v) {
#pragma unroll
    for (int off = 32; off > 0; off >>= 1) v += __shfl_xor(v, off);
    return v;
}

// ---------- K1: fused GEMM  [m;q](576x768) @ W^T(768x768) ----------
// A rows: r<64 -> m[r], else q[r-64].  B row j=(n*192+d): W[n,0,d,:] (K-contiguous).
#define BM 32
#define BN 64
#define BK 64
#define LDSR (BK + 1)

__global__ __launch_bounds__(256) void gemm_mq(
    const float* __restrict__ m, const float* __restrict__ q,
    const float* __restrict__ W, const float* __restrict__ b,
    float* __restrict__ hm, float* __restrict__ hq)
{
    __shared__ float As[BM * LDSR];
    __shared__ float Bs[BN * LDSR];
    const int t  = threadIdx.x;
    const int bm = blockIdx.x, bn = blockIdx.y;
    const int tc = t & 15, tr = t >> 4;

    const float4* aptr[2];
    int arow[2];
#pragma unroll
    for (int u = 0; u < 2; ++u) {
        int fi  = t + 256 * u;
        int row = fi >> 4;           // 0..31
        int kv  = fi & 15;
        int gr  = bm * BM + row;
        const float* base = (gr < IN_CAPS) ? (m + gr * IN_DIM)
                                           : (q + (gr - IN_CAPS) * IN_DIM);
        aptr[u] = reinterpret_cast<const float4*>(base) + kv;
        arow[u] = row * LDSR + 4 * kv;
    }
    const float4* bptr[4];
    int brow[4];
#pragma unroll
    for (int u = 0; u < 4; ++u) {
        int fi = t + 256 * u;
        int jl = fi >> 4;            // 0..63
        int kv = fi & 15;
        int j  = bn * BN + jl;
        int n  = j / DIM_CAPS;
        int d  = j - n * DIM_CAPS;
        bptr[u] = reinterpret_cast<const float4*>(
                      W + (size_t)n * IN_CAPS * DIM_CAPS * IN_DIM + (size_t)d * IN_DIM) + kv;
        brow[u] = jl * LDSR + 4 * kv;
    }

    float acc[2][4] = {};
    for (int ks = 0; ks < IN_DIM / BK; ++ks) {
        float4 av[2], bv[4];
#pragma unroll
        for (int u = 0; u < 2; ++u) av[u] = aptr[u][ks * 16];
#pragma unroll
        for (int u = 0; u < 4; ++u) bv[u] = bptr[u][ks * 16];
        __syncthreads();             // protect previous tile's reads
#pragma unroll
        for (int u = 0; u < 2; ++u) {
            As[arow[u] + 0] = av[u].x; As[arow[u] + 1] = av[u].y;
            As[arow[u] + 2] = av[u].z; As[arow[u] + 3] = av[u].w;
        }
#pragma unroll
        for (int u = 0; u < 4; ++u) {
            Bs[brow[u] + 0] = bv[u].x; Bs[brow[u] + 1] = bv[u].y;
            Bs[brow[u] + 2] = bv[u].z; Bs[brow[u] + 3] = bv[u].w;
        }
        __syncthreads();
#pragma unroll 16
        for (int k = 0; k < BK; ++k) {
            float a0 = As[(2 * tr) * LDSR + k];
            float a1 = As[(2 * tr + 1) * LDSR + k];
            float b0 = Bs[(4 * tc + 0) * LDSR + k];
            float b1 = Bs[(4 * tc + 1) * LDSR + k];
            float b2 = Bs[(4 * tc + 2) * LDSR + k];
            float b3 = Bs[(4 * tc + 3) * LDSR + k];
            acc[0][0] += a0 * b0; acc[0][1] += a0 * b1;
            acc[0][2] += a0 * b2; acc[0][3] += a0 * b3;
            acc[1][0] += a1 * b0; acc[1][1] += a1 * b1;
            acc[1][2] += a1 * b2; acc[1][3] += a1 * b3;
        }
    }
#pragma unroll
    for (int i = 0; i < 2; ++i) {
        int r = bm * BM + 2 * tr + i;
#pragma unroll
        for (int u = 0; u < 4; ++u) {
            int j   = bn * BN + 4 * tc + u;
            float v = acc[i][u];
            if (r < IN_CAPS) {
                int n = j / DIM_CAPS, d = j - n * DIM_CAPS;
                int idx = (n * IN_CAPS + r) * DIM_CAPS + d;
                hm[idx] = v + b[idx];
            } else {
                hq[(r - IN_CAPS) * NDCOLS + j] = v;
            }
        }
    }
}

// ---------- K2: per-(n,c) mean / sum-sq  +  centered transpose xmT[n][d][c] ----------
__global__ __launch_bounds__(256) void stats_xmt(
    const float* __restrict__ hm, float* __restrict__ hmean,
    float* __restrict__ sx, float* __restrict__ xmT)
{
    const int t = threadIdx.x;
    const int r = blockIdx.x * 4 + (t >> 6);     // (n*64+c), 0..255
    const int l = t & 63;
    const int n = r >> 6, c = r & 63;

    const float* row = hm + r * DIM_CAPS;
    float x0 = row[l], x1 = row[l + 64], x2 = row[l + 128];
    float mean = wave_sum(x0 + x1 + x2) * (1.0f / DIM_CAPS);
    float y0 = x0 - mean, y1 = x1 - mean, y2 = x2 - mean;
    float ss = wave_sum(y0 * y0 + y1 * y1 + y2 * y2);
    if (l == 0) { hmean[r] = mean; sx[r] = ss; }

    int base = (n * DIM_CAPS + l) * IN_CAPS + c;
    xmT[base]            = y0;
    xmT[base + 64 * 64]  = y1;
    xmT[base + 128 * 64] = y2;
}

// ---------- K3: routing, one block per query; wave = n, lane = c (and d-triple) ----------
__global__ __launch_bounds__(256) void routing_k(
    const float* __restrict__ hm, const float* __restrict__ xmT,
    const float* __restrict__ hmean, const float* __restrict__ sx,
    const float* __restrict__ hq, float* __restrict__ out)
{
    __shared__ float tq_s[NUM_CAPS][DIM_CAPS];
    __shared__ float v_s[NUM_CAPS][DIM_CAPS];
    __shared__ float a_s[NUM_CAPS][IN_CAPS];

    const int qi = blockIdx.x;
    const int t  = threadIdx.x;
    const int n  = t >> 6;       // wave-uniform
    const int l  = t & 63;

    const float* hqrow = hq + qi * NDCOLS + n * DIM_CAPS;
    float t0 = hqrow[l], t1 = hqrow[l + 64], t2 = hqrow[l + 128];
    tq_s[n][l] = t0; tq_s[n][l + 64] = t1; tq_s[n][l + 128] = t2;

    const float sx_l    = sx[n * IN_CAPS + l];
    const float hmean_l = hmean[n * IN_CAPS + l];
    const float* xcol = xmT + n * DIM_CAPS * IN_CAPS + l;  // stride IN_CAPS over d
    const float* hrow = hm + n * IN_CAPS * DIM_CAPS + l;   // + c*DIM_CAPS

    float a = 0.0f, p;
    {   // initial p
        float tmean = wave_sum(t0 + t1 + t2) * (1.0f / DIM_CAPS);
        float y0 = t0 - tmean, y1 = t1 - tmean, y2 = t2 - tmean;
        float sy = wave_sum(y0 * y0 + y1 * y1 + y2 * y2);
        float acc = 0.0f;
#pragma unroll 8
        for (int d = 0; d < DIM_CAPS; ++d) acc += xcol[d * IN_CAPS] * tq_s[n][d];
        p = tanhf(-acc / sqrtf(sx_l * sy + EPSF));
    }

    for (int it = 0; it < 2; ++it) {
        a_s[n][l] = a;
        __syncthreads();
        float a0 = a_s[0][l], a1 = a_s[1][l], a2 = a_s[2][l], a3 = a_s[3][l];
        __syncthreads();
        float mx = fmaxf(fmaxf(a0, a1), fmaxf(a2, a3));
        float e0 = expf(a0 - mx), e1 = expf(a1 - mx), e2 = expf(a2 - mx), e3 = expf(a3 - mx);
        float esum = e0 + e1 + e2 + e3;
        float mye  = (n == 0) ? e0 : (n == 1) ? e1 : (n == 2) ? e2 : e3;
        float wgt  = mye / esum + p;
        a_s[n][l] = wgt;   // reused per-wave (all cross-wave reads done at barrier 2)

        float hv0 = 0, hv1 = 0, hv2 = 0;
#pragma unroll 4
        for (int c = 0; c < IN_CAPS; ++c) {
            float wv = a_s[n][c];
            const float* hp = hrow + c * DIM_CAPS;
            hv0 += wv * hp[0]; hv1 += wv * hp[64]; hv2 += wv * hp[128];
        }
        float sq = wave_sum(hv0 * hv0 + hv1 * hv1 + hv2 * hv2);
        float scale = sq / ((1.0f + sq) * sqrtf(sq + EPSF));
        float v0 = hv0 * scale, v1 = hv1 * scale, v2 = hv2 * scale;
        v_s[n][l] = v0; v_s[n][l + 64] = v1; v_s[n][l + 128] = v2;
        float vsum = wave_sum(v0 + v1 + v2);

        float accA = 0.0f;
#pragma unroll 8
        for (int d = 0; d < DIM_CAPS; ++d) accA += xcol[d * IN_CAPS] * v_s[n][d];
        float agree = accA + hmean_l * vsum;
        a += p * agree;

        t0 = (t0 + v0) * 0.5f; t1 = (t1 + v1) * 0.5f; t2 = (t2 + v2) * 0.5f;
        tq_s[n][l] = t0; tq_s[n][l + 64] = t1; tq_s[n][l + 128] = t2;

        float tmean = wave_sum(t0 + t1 + t2) * (1.0f / DIM_CAPS);
        float y0 = t0 - tmean, y1 = t1 - tmean, y2 = t2 - tmean;
        float sy = wave_sum(y0 * y0 + y1 * y1 + y2 * y2);
        float accP = 0.0f;
#pragma unroll 8
        for (int d = 0; d < DIM_CAPS; ++d) accP += xcol[d * IN_CAPS] * tq_s[n][d];
        p = tanhf(-accP / sqrtf(sx_l * sy + EPSF));
    }

    // final aggregation (uses hat_m_ij == hm numerically)
    a_s[n][l] = a;
    __syncthreads();
    float a0 = a_s[0][l], a1 = a_s[1][l], a2 = a_s[2][l], a3 = a_s[3][l];
    __syncthreads();
    float mx = fmaxf(fmaxf(a0, a1), fmaxf(a2, a3));
    float e0 = expf(a0 - mx), e1 = expf(a1 - mx), e2 = expf(a2 - mx), e3 = expf(a3 - mx);
    float esum = e0 + e1 + e2 + e3;
    float mye  = (n == 0) ? e0 : (n == 1) ? e1 : (n == 2) ? e2 : e3;
    float wgt  = mye / esum + p;
    a_s[n][l] = wgt;

    float hv0 = 0, hv1 = 0, hv2 = 0;
#pragma unroll 4
    for (int c = 0; c < IN_CAPS; ++c) {
        float wv = a_s[n][c];
        const float* hp = hrow + c * DIM_CAPS;
        hv0 += wv * hp[0]; hv1 += wv * hp[64]; hv2 += wv * hp[128];
    }
    float sq = wave_sum(hv0 * hv0 + hv1 * hv1 + hv2 * hv2);
    float scale = sq / ((1.0f + sq) * sqrtf(sq + EPSF));

    float* orow = out + qi * NDCOLS + n * DIM_CAPS;
    orow[l]       = hv0 * scale;
    orow[l + 64]  = hv1 * scale;
    orow[l + 128] = hv2 * scale;
}

// ---------- launch ----------
extern "C" void kernel_launch(void* const* d_in, const int* in_sizes, int n_in,
                              void* d_out, int out_size, void* d_ws, size_t ws_size,
                              hipStream_t stream) {
    const float* m = (const float*)d_in[0];
    const float* q = (const float*)d_in[1];
    const float* W = (const float*)d_in[2];
    const float* b = (const float*)d_in[3];
    float* out = (float*)d_out;
    float* ws  = (float*)d_ws;

    const int Qn = in_sizes[1] / IN_DIM;           // 512

    float* hm    = ws;                              // 4*64*192
    float* xmT   = ws + 49152;                      // 4*192*64
    float* hmean = ws + 98304;                      // 256
    float* sxv   = ws + 98560;                      // 256
    float* hq    = ws + 98816;                      // Qn*768

    dim3 ggrid((IN_CAPS + Qn + BM - 1) / BM, NDCOLS / BN);
    gemm_mq<<<ggrid, 256, 0, stream>>>(m, q, W, b, hm, hq);
    stats_xmt<<<64, 256, 0, stream>>>(hm, hmean, sxv, xmT);
    routing_k<<<Qn, 256, 0, stream>>>(hm, xmT, hmean, sxv, hq, out);
}

// Round 3
// 253.720 us; speedup vs baseline: 1.0255x; 1.0255x over previous
//
#include <hip/hip_runtime.h>
#include <hip/hip_bf16.h>

#define EPSF 1e-8f

__device__ __forceinline__ float wave_sum(float v) {
#pragma unroll
    for (int off = 32; off > 0; off >>= 1) v += __shfl_xor(v, off);
    return v;
}

// ---------------- GEMM: [m;q](576x768) @ W^T(768x768) -> hm(+bias), hq ----------------
__global__ __launch_bounds__(256) void gemm_mq(
    const float* __restrict__ m, const float* __restrict__ q,
    const float* __restrict__ W, const float* __restrict__ b,
    float* __restrict__ hm, float* __restrict__ hq)
{
    __shared__ __align__(16) float As[32][32];   // [k][m]
    __shared__ __align__(16) float Bs[32][64];   // [k][n]
    const int t  = threadIdx.x;
    const int bm = blockIdx.x, bn = blockIdx.y;
    const int tc = t & 15, tr = t >> 4;

    // A staging: row = t&31, k-quad = (t>>5)*4
    const int arow = t & 31;
    const int ak   = (t >> 5) << 2;
    const int gr   = bm * 32 + arow;
    const float* abase = ((gr < 64) ? (m + gr * 768) : (q + (gr - 64) * 768)) + ak;

    // B staging: col = t&63, two k-quads
    const int jl  = t & 63;
    const int bk0 = ((t >> 6) & 3) << 2;
    const int bk1 = bk0 + 16;
    const float* bbase;
    {
        int j = bn * 64 + jl;
        int n = j / 192, d = j - n * 192;
        bbase = W + (size_t)n * 64 * 192 * 768 + (size_t)d * 768;
    }

    float acc[2][4] = {};
    for (int ks = 0; ks < 24; ++ks) {
        float4 av  = *(const float4*)(abase + ks * 32);
        float4 bv0 = *(const float4*)(bbase + ks * 32 + bk0);
        float4 bv1 = *(const float4*)(bbase + ks * 32 + bk1);
        __syncthreads();   // protect previous tile's reads
        As[ak + 0][arow] = av.x;  As[ak + 1][arow] = av.y;
        As[ak + 2][arow] = av.z;  As[ak + 3][arow] = av.w;
        Bs[bk0 + 0][jl] = bv0.x;  Bs[bk0 + 1][jl] = bv0.y;
        Bs[bk0 + 2][jl] = bv0.z;  Bs[bk0 + 3][jl] = bv0.w;
        Bs[bk1 + 0][jl] = bv1.x;  Bs[bk1 + 1][jl] = bv1.y;
        Bs[bk1 + 2][jl] = bv1.z;  Bs[bk1 + 3][jl] = bv1.w;
        __syncthreads();
#pragma unroll
        for (int k = 0; k < 32; ++k) {
            float2 a2 = *(const float2*)&As[k][2 * tr];
            float4 b4 = *(const float4*)&Bs[k][4 * tc];
            acc[0][0] += a2.x * b4.x; acc[0][1] += a2.x * b4.y;
            acc[0][2] += a2.x * b4.z; acc[0][3] += a2.x * b4.w;
            acc[1][0] += a2.y * b4.x; acc[1][1] += a2.y * b4.y;
            acc[1][2] += a2.y * b4.z; acc[1][3] += a2.y * b4.w;
        }
    }
#pragma unroll
    for (int i = 0; i < 2; ++i) {
        int r = bm * 32 + 2 * tr + i;
#pragma unroll
        for (int u = 0; u < 4; ++u) {
            int j = bn * 64 + 4 * tc + u;
            float v = acc[i][u];
            if (r < 64) {
                int n = j / 192, d = j - n * 192;
                int idx = (n * 64 + r) * 192 + d;
                hm[idx] = v + b[idx];
            } else {
                hq[(r - 64) * 768 + j] = v;
            }
        }
    }
}

// ---------------- routing round kernel ----------------
// block = (query-group qg, capsule n); 4 waves, wave w handles query qg*4+w.
// hs: hm[n] 64x192 staged with XOR swizzle  hs[c][d ^ ((c&7)<<2)]
//   pass B (per-lane c, dot row c with wbuf):  float4 slot k -> k ^ (c&7)   (b128, bank-free)
//   pass A (per-lane l over d, serial c):      li = l ^ ((c&7)<<2)          (2-way, free)
template<int R>
__global__ __launch_bounds__(256) void route_round(
    const float* __restrict__ hm, const float* __restrict__ hq,
    float* __restrict__ a_g, float* __restrict__ p_g,
    float* __restrict__ tq_g, float* __restrict__ out)
{
    __shared__ __align__(16) float hs[64 * 192];
    __shared__ __align__(16) float wbuf[4][192];
    __shared__ __align__(16) float wgt_s[4][64];

    const int bid = blockIdx.x;
    const int n = bid & 3, qg = bid >> 2;
    const int t = threadIdx.x, w = t >> 6, l = t & 63;
    const int q = qg * 4 + w;

    // stage hm[n] -> hs (swizzled)
    {
        const float4* hsrc = (const float4*)(hm + n * 64 * 192);
        float4* hs4 = (float4*)hs;
#pragma unroll
        for (int i = 0; i < 12; ++i) {
            int f  = t + 256 * i;
            int c  = f / 48;
            int d4 = f - c * 48;
            hs4[c * 48 + (d4 ^ (c & 7))] = hsrc[f];
        }
    }
    __syncthreads();

    const int xo = l & 7;
    const float4* hrow4 = (const float4*)(hs + l * 192);

    auto passB = [&]() -> float {   // dot(hs row l, wbuf[w])
        const float4* wv4 = (const float4*)wbuf[w];
        float4 acc = {0.f, 0.f, 0.f, 0.f};
#pragma unroll 8
        for (int k = 0; k < 48; ++k) {
            float4 h  = hrow4[k ^ xo];
            float4 wv = wv4[k];
            acc.x += h.x * wv.x; acc.y += h.y * wv.y;
            acc.z += h.z * wv.z; acc.w += h.w * wv.w;
        }
        return acc.x + acc.y + acc.z + acc.w;
    };

    // per-lane (c = l) row stats: sx = sum_d (hm - mean)^2
    float sx_c = 0.0f;
    if (R < 3) {
        float4 s = {0.f, 0.f, 0.f, 0.f};
#pragma unroll 8
        for (int k = 0; k < 48; ++k) {
            float4 h = hrow4[k ^ xo];
            s.x += h.x; s.y += h.y; s.z += h.z; s.w += h.w;
        }
        float mean = (s.x + s.y + s.z + s.w) * (1.0f / 192.0f);
        float4 ss = {0.f, 0.f, 0.f, 0.f};
#pragma unroll 8
        for (int k = 0; k < 48; ++k) {
            float4 h = hrow4[k ^ xo];
            float dx = h.x - mean, dy = h.y - mean, dz = h.z - mean, dw = h.w - mean;
            ss.x += dx * dx; ss.y += dy * dy; ss.z += dz * dz; ss.w += dw * dw;
        }
        sx_c = ss.x + ss.y + ss.z + ss.w;
    }

    float t0 = 0.f, t1 = 0.f, t2 = 0.f;
    if (R == 1) {
        const float* ts = hq + q * 768 + n * 192;
        t0 = ts[l]; t1 = ts[l + 64]; t2 = ts[l + 128];
    } else if (R == 2) {
        const float* ts = tq_g + q * 768 + n * 192;
        t0 = ts[l]; t1 = ts[l + 64]; t2 = ts[l + 128];
    }

    float p_c, dsm, a_prev;
    if (R == 1) {
        a_prev = 0.0f; dsm = 0.25f;                 // softmax(0) over 4
        float tmean = wave_sum(t0 + t1 + t2) * (1.0f / 192.0f);
        float y0 = t0 - tmean, y1 = t1 - tmean, y2 = t2 - tmean;
        float sy = wave_sum(y0 * y0 + y1 * y1 + y2 * y2);
        wbuf[w][l] = y0; wbuf[w][l + 64] = y1; wbuf[w][l + 128] = y2;
        float num = passB();                        // = sum_d xm*ym  (sum_d xm = 0)
        p_c = tanhf(-num * rsqrtf(sx_c * sy + EPSF));
    } else {
        float a0 = a_g[q * 256 + l],       a1 = a_g[q * 256 + 64 + l];
        float a2 = a_g[q * 256 + 128 + l], a3 = a_g[q * 256 + 192 + l];
        a_prev = (n == 0) ? a0 : (n == 1) ? a1 : (n == 2) ? a2 : a3;
        float mx = fmaxf(fmaxf(a0, a1), fmaxf(a2, a3));
        float e0 = expf(a0 - mx), e1 = expf(a1 - mx), e2 = expf(a2 - mx), e3 = expf(a3 - mx);
        dsm = ((n == 0) ? e0 : (n == 1) ? e1 : (n == 2) ? e2 : e3) / (e0 + e1 + e2 + e3);
        p_c = p_g[q * 256 + n * 64 + l];
    }

    float wgt = dsm + p_c;
    wgt_s[w][l] = wgt;

    // pass A: hv[d] = sum_c wgt[c] * hm[c][d]
    float hv0 = 0.f, hv1 = 0.f, hv2 = 0.f;
#pragma unroll 8
    for (int c = 0; c < 64; ++c) {
        float wv = wgt_s[w][c];
        const float* hr = hs + c * 192;
        int li = l ^ ((c & 7) << 2);
        hv0 += wv * hr[li]; hv1 += wv * hr[li + 64]; hv2 += wv * hr[li + 128];
    }
    float sq = wave_sum(hv0 * hv0 + hv1 * hv1 + hv2 * hv2);
    float scale = sq / ((1.0f + sq) * sqrtf(sq + EPSF));
    float v0 = hv0 * scale, v1 = hv1 * scale, v2 = hv2 * scale;

    if (R == 3) {
        float* orow = out + q * 768 + n * 192;
        orow[l] = v0; orow[l + 64] = v1; orow[l + 128] = v2;
        return;
    }

    // agree[c] = sum_d hm[c][d] * v[d]
    wbuf[w][l] = v0; wbuf[w][l + 64] = v1; wbuf[w][l + 128] = v2;
    float agree = passB();
    a_g[q * 256 + n * 64 + l] = a_prev + p_c * agree;

    // tq update + next p
    t0 = (t0 + v0) * 0.5f; t1 = (t1 + v1) * 0.5f; t2 = (t2 + v2) * 0.5f;
    if (R == 1) {
        float* ts = tq_g + q * 768 + n * 192;
        ts[l] = t0; ts[l + 64] = t1; ts[l + 128] = t2;
    }
    float tmean = wave_sum(t0 + t1 + t2) * (1.0f / 192.0f);
    float y0 = t0 - tmean, y1 = t1 - tmean, y2 = t2 - tmean;
    float sy = wave_sum(y0 * y0 + y1 * y1 + y2 * y2);
    wbuf[w][l] = y0; wbuf[w][l + 64] = y1; wbuf[w][l + 128] = y2;
    float num = passB();
    p_g[q * 256 + n * 64 + l] = tanhf(-num * rsqrtf(sx_c * sy + EPSF));
}

// ---------------- launch ----------------
extern "C" void kernel_launch(void* const* d_in, const int* in_sizes, int n_in,
                              void* d_out, int out_size, void* d_ws, size_t ws_size,
                              hipStream_t stream) {
    const float* m = (const float*)d_in[0];
    const float* q = (const float*)d_in[1];
    const float* W = (const float*)d_in[2];
    const float* b = (const float*)d_in[3];
    float* out = (float*)d_out;
    float* ws  = (float*)d_ws;

    float* hm   = ws;                 //  49152
    float* hq   = ws + 49152;         // 393216
    float* a_g  = ws + 442368;        // 131072
    float* p_g  = ws + 573440;        // 131072
    float* tq_g = ws + 704512;        // 393216

    dim3 ggrid(18, 12);
    gemm_mq<<<ggrid, 256, 0, stream>>>(m, q, W, b, hm, hq);
    route_round<1><<<512, 256, 0, stream>>>(hm, hq, a_g, p_g, tq_g, out);
    route_round<2><<<512, 256, 0, stream>>>(hm, hq, a_g, p_g, tq_g, out);
    route_round<3><<<512, 256, 0, stream>>>(hm, hq, a_g, p_g, tq_g, out);
}

// Round 4
// 247.241 us; speedup vs baseline: 1.0524x; 1.0262x over previous
//
#include <hip/hip_runtime.h>
#include <hip/hip_bf16.h>

#define EPSF 1e-8f

__device__ __forceinline__ float wave_sum(float v) {
#pragma unroll
    for (int off = 32; off > 0; off >>= 1) v += __shfl_xor(v, off);
    return v;
}

__device__ __forceinline__ unsigned f2bf(float x) {           // RNE f32->bf16
    unsigned u = __builtin_bit_cast(unsigned, x);
    u += 0x7fffu + ((u >> 16) & 1u);
    return u >> 16;
}
__device__ __forceinline__ float bflo(unsigned u) {
    return __builtin_bit_cast(float, u << 16);
}
__device__ __forceinline__ float bfhi(unsigned u) {
    return __builtin_bit_cast(float, u & 0xffff0000u);
}

// ---------------- GEMM: [m;q](576x768) @ W^T(768x768) -> hm(+bias), hq ----------------
__global__ __launch_bounds__(256) void gemm_mq(
    const float* __restrict__ m, const float* __restrict__ q,
    const float* __restrict__ W, const float* __restrict__ b,
    float* __restrict__ hm, float* __restrict__ hq)
{
    __shared__ __align__(16) float As[32][32];   // [k][m]
    __shared__ __align__(16) float Bs[32][64];   // [k][n]
    const int t  = threadIdx.x;
    const int bm = blockIdx.x, bn = blockIdx.y;
    const int tc = t & 15, tr = t >> 4;

    const int arow = t & 31;
    const int ak   = (t >> 5) << 2;
    const int gr   = bm * 32 + arow;
    const float* abase = ((gr < 64) ? (m + gr * 768) : (q + (gr - 64) * 768)) + ak;

    const int jl  = t & 63;
    const int bk0 = ((t >> 6) & 3) << 2;
    const int bk1 = bk0 + 16;
    const float* bbase;
    {
        int j = bn * 64 + jl;
        int n = j / 192, d = j - n * 192;
        bbase = W + (size_t)n * 64 * 192 * 768 + (size_t)d * 768;
    }

    float acc[2][4] = {};
    for (int ks = 0; ks < 24; ++ks) {
        float4 av  = *(const float4*)(abase + ks * 32);
        float4 bv0 = *(const float4*)(bbase + ks * 32 + bk0);
        float4 bv1 = *(const float4*)(bbase + ks * 32 + bk1);
        __syncthreads();
        As[ak + 0][arow] = av.x;  As[ak + 1][arow] = av.y;
        As[ak + 2][arow] = av.z;  As[ak + 3][arow] = av.w;
        Bs[bk0 + 0][jl] = bv0.x;  Bs[bk0 + 1][jl] = bv0.y;
        Bs[bk0 + 2][jl] = bv0.z;  Bs[bk0 + 3][jl] = bv0.w;
        Bs[bk1 + 0][jl] = bv1.x;  Bs[bk1 + 1][jl] = bv1.y;
        Bs[bk1 + 2][jl] = bv1.z;  Bs[bk1 + 3][jl] = bv1.w;
        __syncthreads();
#pragma unroll
        for (int k = 0; k < 32; ++k) {
            float2 a2 = *(const float2*)&As[k][2 * tr];
            float4 b4 = *(const float4*)&Bs[k][4 * tc];
            acc[0][0] += a2.x * b4.x; acc[0][1] += a2.x * b4.y;
            acc[0][2] += a2.x * b4.z; acc[0][3] += a2.x * b4.w;
            acc[1][0] += a2.y * b4.x; acc[1][1] += a2.y * b4.y;
            acc[1][2] += a2.y * b4.z; acc[1][3] += a2.y * b4.w;
        }
    }
#pragma unroll
    for (int i = 0; i < 2; ++i) {
        int r = bm * 32 + 2 * tr + i;
#pragma unroll
        for (int u = 0; u < 4; ++u) {
            int j = bn * 64 + 4 * tc + u;
            float v = acc[i][u];
            if (r < 64) {
                int n = j / 192, d = j - n * 192;
                int idx = (n * 64 + r) * 192 + d;
                hm[idx] = v + b[idx];
            } else {
                hq[(r - 64) * 768 + j] = v;
            }
        }
    }
}

// ---------------- fully fused routing: all 3 rounds, 2 queries x 4 capsules per block ----
// hm staged once as bf16-packed rows (96 u32 words / row), slot-swizzled k ^ (row&7).
__global__ __launch_bounds__(512) void route_fused(
    const float* __restrict__ hm, const float* __restrict__ hq,
    float* __restrict__ out)
{
    __shared__ __align__(16) uint4 hs4[4 * 64 * 24];   // 96 KB
    __shared__ __align__(16) float wbuf[8][192];       //  6 KB (per-wave vector)
    __shared__ __align__(16) float wgt_x[8][64];       //  2 KB
    __shared__ __align__(16) float a_x[2][4][64];      //  2 KB

    const int t = threadIdx.x, w = t >> 6, l = t & 63;
    const int ql = w >> 2, n = w & 3;
    const int q  = blockIdx.x * 2 + ql;

    // ---- stage all of hm (196 KB f32 -> 96 KB bf16, swizzled) ----
    {
        const float4* src = (const float4*)hm;
#pragma unroll
        for (int i = 0; i < 12; ++i) {
            int f = t + 512 * i;               // packed-slot id 0..6143
            int r = f / 24, k = f - r * 24;    // row (n*64+c), slot
            float4 x0 = src[f * 2];
            float4 x1 = src[f * 2 + 1];
            uint4 pk;
            pk.x = f2bf(x0.x) | (f2bf(x0.y) << 16);
            pk.y = f2bf(x0.z) | (f2bf(x0.w) << 16);
            pk.z = f2bf(x1.x) | (f2bf(x1.y) << 16);
            pk.w = f2bf(x1.z) | (f2bf(x1.w) << 16);
            hs4[r * 24 + (k ^ (r & 7))] = pk;
        }
    }
    __syncthreads();

    const uint4* myrow = hs4 + (n * 64 + l) * 24;
    const int xo = l & 7;

    // dot(my hm row, wbuf[w])
    auto dotrow = [&]() -> float {
        float4 acc = {0.f, 0.f, 0.f, 0.f};
#pragma unroll 6
        for (int k = 0; k < 24; ++k) {
            uint4 h = myrow[k ^ xo];
            float4 wa = *(const float4*)&wbuf[w][k * 8];
            float4 wb = *(const float4*)&wbuf[w][k * 8 + 4];
            acc.x += bflo(h.x) * wa.x; acc.y += bfhi(h.x) * wa.y;
            acc.z += bflo(h.y) * wa.z; acc.w += bfhi(h.y) * wa.w;
            acc.x += bflo(h.z) * wb.x; acc.y += bfhi(h.z) * wb.y;
            acc.z += bflo(h.w) * wb.z; acc.w += bfhi(h.w) * wb.w;
        }
        return (acc.x + acc.y) + (acc.z + acc.w);
    };

    // ---- per-lane row stats: sx = sum h^2 - 192*mean^2 ----
    float s1 = 0.f, s2 = 0.f;
#pragma unroll 6
    for (int k = 0; k < 24; ++k) {
        uint4 h = myrow[k ^ xo];
        float e0 = bflo(h.x), e1 = bfhi(h.x), e2 = bflo(h.y), e3 = bfhi(h.y);
        float e4 = bflo(h.z), e5 = bfhi(h.z), e6 = bflo(h.w), e7 = bfhi(h.w);
        s1 += ((e0 + e1) + (e2 + e3)) + ((e4 + e5) + (e6 + e7));
        s2 += ((e0*e0 + e1*e1) + (e2*e2 + e3*e3)) + ((e4*e4 + e5*e5) + (e6*e6 + e7*e7));
    }
    float mean = s1 * (1.0f / 192.0f);
    float sx_c = s2 - 192.0f * mean * mean;

    // ---- load tq = hq row, initial p ----
    const float* tsrc = hq + q * 768 + n * 192;
    float t0 = tsrc[l], t1 = tsrc[l + 64], t2 = tsrc[l + 128];

    float tmean = wave_sum(t0 + t1 + t2) * (1.0f / 192.0f);
    float y0 = t0 - tmean, y1 = t1 - tmean, y2 = t2 - tmean;
    float sy = wave_sum(y0 * y0 + y1 * y1 + y2 * y2);
    wbuf[w][l] = y0; wbuf[w][l + 64] = y1; wbuf[w][l + 128] = y2;
    float p = tanhf(-dotrow() * rsqrtf(sx_c * sy + EPSF));
    float a = 0.0f;

    // passA addressing precompute
    const unsigned* rowbase = (const unsigned*)hs4 + n * 64 * 96;
    const int sub = (l >> 1) & 3;
    const int g   = l >> 3;
    const unsigned sh = (l & 1) ? 0u : 16u;

    float dsm = 0.25f;                      // softmax(0) over 4
    for (int r = 0; r < 3; ++r) {
        if (r > 0) {
            a_x[ql][n][l] = a;
            __syncthreads();
            float a0 = a_x[ql][0][l], a1 = a_x[ql][1][l];
            float a2 = a_x[ql][2][l], a3 = a_x[ql][3][l];
            __syncthreads();
            float mx = fmaxf(fmaxf(a0, a1), fmaxf(a2, a3));
            float e0 = __expf(a0 - mx), e1 = __expf(a1 - mx);
            float e2 = __expf(a2 - mx), e3 = __expf(a3 - mx);
            float my = (n == 0) ? e0 : (n == 1) ? e1 : (n == 2) ? e2 : e3;
            dsm = my / (e0 + e1 + e2 + e3);
        }
        float wgt = dsm + p;
        wgt_x[w][l] = wgt;

        // passA: hv[d] = sum_c wgt[c]*hm[c][d]   (d = l, l+64, l+128)
        float hv0 = 0.f, hv1 = 0.f, hv2 = 0.f;
#pragma unroll 8
        for (int c = 0; c < 64; ++c) {
            float wv = wgt_x[w][c];
            int base = c * 96 + ((g ^ (c & 7)) << 2) + sub;
            unsigned u0 = rowbase[base];
            unsigned u1 = rowbase[base + 32];
            unsigned u2 = rowbase[base + 64];
            float h0 = __builtin_bit_cast(float, (u0 << sh) & 0xffff0000u);
            float h1 = __builtin_bit_cast(float, (u1 << sh) & 0xffff0000u);
            float h2 = __builtin_bit_cast(float, (u2 << sh) & 0xffff0000u);
            hv0 += wv * h0; hv1 += wv * h1; hv2 += wv * h2;
        }
        float sq = wave_sum(hv0 * hv0 + hv1 * hv1 + hv2 * hv2);
        float scale = sq / ((1.0f + sq) * sqrtf(sq + EPSF));
        float v0 = hv0 * scale, v1 = hv1 * scale, v2 = hv2 * scale;

        if (r == 2) {
            float* orow = out + q * 768 + n * 192;
            orow[l] = v0; orow[l + 64] = v1; orow[l + 128] = v2;
            break;
        }

        // agree = dot(hm row, v);  a += p*agree
        wbuf[w][l] = v0; wbuf[w][l + 64] = v1; wbuf[w][l + 128] = v2;
        float agree = dotrow();
        a += p * agree;

        // tq update + next p
        t0 = (t0 + v0) * 0.5f; t1 = (t1 + v1) * 0.5f; t2 = (t2 + v2) * 0.5f;
        float tm2 = wave_sum(t0 + t1 + t2) * (1.0f / 192.0f);
        float z0 = t0 - tm2, z1 = t1 - tm2, z2 = t2 - tm2;
        float sy2 = wave_sum(z0 * z0 + z1 * z1 + z2 * z2);
        wbuf[w][l] = z0; wbuf[w][l + 64] = z1; wbuf[w][l + 128] = z2;
        p = tanhf(-dotrow() * rsqrtf(sx_c * sy2 + EPSF));
    }
}

// ---------------- launch ----------------
extern "C" void kernel_launch(void* const* d_in, const int* in_sizes, int n_in,
                              void* d_out, int out_size, void* d_ws, size_t ws_size,
                              hipStream_t stream) {
    const float* m = (const float*)d_in[0];
    const float* q = (const float*)d_in[1];
    const float* W = (const float*)d_in[2];
    const float* b = (const float*)d_in[3];
    float* out = (float*)d_out;
    float* ws  = (float*)d_ws;

    const int Qn = in_sizes[1] / 768;      // 512

    float* hm = ws;                         // 4*64*192 = 49152 floats
    float* hq = ws + 49152;                 // Qn*768

    dim3 ggrid(18, 12);
    gemm_mq<<<ggrid, 256, 0, stream>>>(m, q, W, b, hm, hq);
    route_fused<<<Qn / 2, 512, 0, stream>>>(hm, hq, out);
}

// Round 5
// 227.654 us; speedup vs baseline: 1.1429x; 1.0860x over previous
//
#include <hip/hip_runtime.h>
#include <hip/hip_bf16.h>

#define EPSF 1e-8f

__device__ __forceinline__ float wave_sum(float v) {
#pragma unroll
    for (int off = 32; off > 0; off >>= 1) v += __shfl_xor(v, off);
    return v;
}

__device__ __forceinline__ unsigned f2bf(float x) {           // RNE f32->bf16
    unsigned u = __builtin_bit_cast(unsigned, x);
    u += 0x7fffu + ((u >> 16) & 1u);
    return u >> 16;
}
__device__ __forceinline__ float bflo(unsigned u) {
    return __builtin_bit_cast(float, u << 16);
}
__device__ __forceinline__ float bfhi(unsigned u) {
    return __builtin_bit_cast(float, u & 0xffff0000u);
}

// ---------------- GEMM: [m;q](576x768) @ W^T(768x768) -> hm(+bias), hq ----------------
// Double-buffered LDS: one barrier per k-tile.
__global__ __launch_bounds__(256) void gemm_mq(
    const float* __restrict__ m, const float* __restrict__ q,
    const float* __restrict__ W, const float* __restrict__ b,
    float* __restrict__ hm, float* __restrict__ hq)
{
    __shared__ __align__(16) float As[2][32][32];   // [buf][k][m]
    __shared__ __align__(16) float Bs[2][32][64];   // [buf][k][n]
    const int t  = threadIdx.x;
    const int bm = blockIdx.x, bn = blockIdx.y;
    const int tc = t & 15, tr = t >> 4;

    const int arow = t & 31;
    const int ak   = (t >> 5) << 2;
    const int gr   = bm * 32 + arow;
    const float* abase = ((gr < 64) ? (m + gr * 768) : (q + (gr - 64) * 768)) + ak;

    const int jl  = t & 63;
    const int bk0 = ((t >> 6) & 3) << 2;
    const int bk1 = bk0 + 16;
    const float* bbase;
    {
        int j = bn * 64 + jl;
        int n = j / 192, d = j - n * 192;
        bbase = W + (size_t)n * 64 * 192 * 768 + (size_t)d * 768;
    }

    // preload + stage tile 0
    {
        float4 av  = *(const float4*)(abase);
        float4 bv0 = *(const float4*)(bbase + bk0);
        float4 bv1 = *(const float4*)(bbase + bk1);
        As[0][ak + 0][arow] = av.x;  As[0][ak + 1][arow] = av.y;
        As[0][ak + 2][arow] = av.z;  As[0][ak + 3][arow] = av.w;
        Bs[0][bk0 + 0][jl] = bv0.x;  Bs[0][bk0 + 1][jl] = bv0.y;
        Bs[0][bk0 + 2][jl] = bv0.z;  Bs[0][bk0 + 3][jl] = bv0.w;
        Bs[0][bk1 + 0][jl] = bv1.x;  Bs[0][bk1 + 1][jl] = bv1.y;
        Bs[0][bk1 + 2][jl] = bv1.z;  Bs[0][bk1 + 3][jl] = bv1.w;
    }
    __syncthreads();

    float acc[2][4] = {};
    for (int ks = 0; ks < 24; ++ks) {
        const int cur = ks & 1;
        float4 av, bv0, bv1;
        if (ks < 23) {
            av  = *(const float4*)(abase + (ks + 1) * 32);
            bv0 = *(const float4*)(bbase + (ks + 1) * 32 + bk0);
            bv1 = *(const float4*)(bbase + (ks + 1) * 32 + bk1);
        }
#pragma unroll
        for (int k = 0; k < 32; ++k) {
            float2 a2 = *(const float2*)&As[cur][k][2 * tr];
            float4 b4 = *(const float4*)&Bs[cur][k][4 * tc];
            acc[0][0] += a2.x * b4.x; acc[0][1] += a2.x * b4.y;
            acc[0][2] += a2.x * b4.z; acc[0][3] += a2.x * b4.w;
            acc[1][0] += a2.y * b4.x; acc[1][1] += a2.y * b4.y;
            acc[1][2] += a2.y * b4.z; acc[1][3] += a2.y * b4.w;
        }
        if (ks < 23) {
            const int nxt = cur ^ 1;
            As[nxt][ak + 0][arow] = av.x;  As[nxt][ak + 1][arow] = av.y;
            As[nxt][ak + 2][arow] = av.z;  As[nxt][ak + 3][arow] = av.w;
            Bs[nxt][bk0 + 0][jl] = bv0.x;  Bs[nxt][bk0 + 1][jl] = bv0.y;
            Bs[nxt][bk0 + 2][jl] = bv0.z;  Bs[nxt][bk0 + 3][jl] = bv0.w;
            Bs[nxt][bk1 + 0][jl] = bv1.x;  Bs[nxt][bk1 + 1][jl] = bv1.y;
            Bs[nxt][bk1 + 2][jl] = bv1.z;  Bs[nxt][bk1 + 3][jl] = bv1.w;
            __syncthreads();
        }
    }
#pragma unroll
    for (int i = 0; i < 2; ++i) {
        int r = bm * 32 + 2 * tr + i;
#pragma unroll
        for (int u = 0; u < 4; ++u) {
            int j = bn * 64 + 4 * tc + u;
            float v = acc[i][u];
            if (r < 64) {
                int n = j / 192, d = j - n * 192;
                int idx = (n * 64 + r) * 192 + d;
                hm[idx] = v + b[idx];
            } else {
                hq[(r - 64) * 768 + j] = v;
            }
        }
    }
}

// ---------------- fully fused routing: all 3 rounds, 2 queries x 4 capsules per block ----
// hm staged once as bf16-packed rows (96 u32 / row), uint4-slot swizzle k ^ (row&7).
// tq/v held 4-wide per lane (lanes 0..47: d = 4l..4l+3); pearson via D/tmean recursion.
__global__ __launch_bounds__(512) void route_fused(
    const float* __restrict__ hm, const float* __restrict__ hq,
    float* __restrict__ out)
{
    __shared__ __align__(16) uint4 hs4[4 * 64 * 24];   // 96 KB
    __shared__ __align__(16) float wbuf[8][192];       //  6 KB (per-wave vector)
    __shared__ __align__(16) float wgt_x[8][64];       //  2 KB
    __shared__ __align__(16) float a_x[2][4][64];      //  2 KB

    const int t = threadIdx.x, w = t >> 6, l = t & 63;
    const int ql = w >> 2, n = w & 3;
    const int q  = blockIdx.x * 2 + ql;

    // ---- stage all of hm (192 KB f32 -> 96 KB bf16, swizzled) ----
    {
        const float4* src = (const float4*)hm;
#pragma unroll
        for (int i = 0; i < 12; ++i) {
            int f = t + 512 * i;               // packed-slot id 0..6143
            int r = f / 24, k = f - r * 24;    // row (n*64+c), slot
            float4 x0 = src[f * 2];
            float4 x1 = src[f * 2 + 1];
            uint4 pk;
            pk.x = f2bf(x0.x) | (f2bf(x0.y) << 16);
            pk.y = f2bf(x0.z) | (f2bf(x0.w) << 16);
            pk.z = f2bf(x1.x) | (f2bf(x1.y) << 16);
            pk.w = f2bf(x1.z) | (f2bf(x1.w) << 16);
            hs4[r * 24 + (k ^ (r & 7))] = pk;
        }
    }
    __syncthreads();

    const uint4* myrow = hs4 + (n * 64 + l) * 24;
    const int xo = l & 7;

    // dot(my hm row, wbuf[w])
    auto dotrow = [&]() -> float {
        float4 acc = {0.f, 0.f, 0.f, 0.f};
#pragma unroll 6
        for (int k = 0; k < 24; ++k) {
            uint4 h = myrow[k ^ xo];
            float4 wa = *(const float4*)&wbuf[w][k * 8];
            float4 wb = *(const float4*)&wbuf[w][k * 8 + 4];
            acc.x += bflo(h.x) * wa.x; acc.y += bfhi(h.x) * wa.y;
            acc.z += bflo(h.y) * wa.z; acc.w += bfhi(h.y) * wa.w;
            acc.x += bflo(h.z) * wb.x; acc.y += bfhi(h.z) * wb.y;
            acc.z += bflo(h.w) * wb.z; acc.w += bfhi(h.w) * wb.w;
        }
        return (acc.x + acc.y) + (acc.z + acc.w);
    };

    // ---- per-lane row stats: S = sum hm, sx = sum hm^2 - 192*mean^2 ----
    float s1 = 0.f, s2 = 0.f;
#pragma unroll 6
    for (int k = 0; k < 24; ++k) {
        uint4 h = myrow[k ^ xo];
        float e0 = bflo(h.x), e1 = bfhi(h.x), e2 = bflo(h.y), e3 = bfhi(h.y);
        float e4 = bflo(h.z), e5 = bfhi(h.z), e6 = bflo(h.w), e7 = bfhi(h.w);
        s1 += ((e0 + e1) + (e2 + e3)) + ((e4 + e5) + (e6 + e7));
        s2 += ((e0*e0 + e1*e1) + (e2*e2 + e3*e3)) + ((e4*e4 + e5*e5) + (e6*e6 + e7*e7));
    }
    const float S = s1;
    const float hmmean = s1 * (1.0f / 192.0f);
    const float sx_c = s2 - 192.0f * hmmean * hmmean;

    // ---- tq in 4-wide layout (lanes 0..47) ----
    const bool act = (l < 48);
    float t4x = 0.f, t4y = 0.f, t4z = 0.f, t4w = 0.f;
    if (act) {
        float4 tv = *(const float4*)(hq + q * 768 + n * 192 + 4 * l);
        t4x = tv.x; t4y = tv.y; t4z = tv.z; t4w = tv.w;
        *(float4*)&wbuf[w][4 * l] = tv;          // raw tq for D0
    }
    float tmean = wave_sum((t4x + t4y) + (t4z + t4w)) * (1.0f / 192.0f);
    float t2s   = wave_sum((t4x*t4x + t4y*t4y) + (t4z*t4z + t4w*t4w));
    float sy    = t2s - 192.0f * tmean * tmean;
    float D     = dotrow();                       // dot(hm_row, tq)
    float p     = tanhf(-(D - tmean * S) * rsqrtf(sx_c * sy + EPSF));
    float a = 0.0f, dsm = 0.25f;                  // softmax(0) over 4

    // passA addressing: lane l<48 covers d = 4l..4l+3  (uint2 within one swizzled quad)
    const unsigned* rowbase = (const unsigned*)hs4 + n * 64 * 96;
    const int qk   = l >> 1;           // logical quad
    const int wsel = (l & 1) << 1;     // word-in-quad 0 or 2

    for (int r = 0; r < 3; ++r) {
        if (r > 0) {
            a_x[ql][n][l] = a;
            __syncthreads();
            float a0 = a_x[ql][0][l], a1 = a_x[ql][1][l];
            float a2 = a_x[ql][2][l], a3 = a_x[ql][3][l];
            __syncthreads();
            float mx = fmaxf(fmaxf(a0, a1), fmaxf(a2, a3));
            float e0 = __expf(a0 - mx), e1 = __expf(a1 - mx);
            float e2 = __expf(a2 - mx), e3 = __expf(a3 - mx);
            float my = (n == 0) ? e0 : (n == 1) ? e1 : (n == 2) ? e2 : e3;
            dsm = my / (e0 + e1 + e2 + e3);
        }
        wgt_x[w][l] = dsm + p;

        // passA: hv[d] = sum_c wgt[c]*hm[c][d], d = 4l..4l+3
        float hv0 = 0.f, hv1 = 0.f, hv2 = 0.f, hv3 = 0.f;
        if (act) {
#pragma unroll 8
            for (int c = 0; c < 64; ++c) {
                float wv = wgt_x[w][c];
                int base = c * 96 + ((qk ^ (c & 7)) << 2) + wsel;
                uint2 u = *(const uint2*)(rowbase + base);
                hv0 += wv * bflo(u.x); hv1 += wv * bfhi(u.x);
                hv2 += wv * bflo(u.y); hv3 += wv * bfhi(u.y);
            }
        }
        float sq = wave_sum((hv0*hv0 + hv1*hv1) + (hv2*hv2 + hv3*hv3));
        float scale = sq / ((1.0f + sq) * sqrtf(sq + EPSF));
        float v0 = hv0 * scale, v1 = hv1 * scale, v2 = hv2 * scale, v3 = hv3 * scale;

        if (r == 2) {
            if (act) {
                float4 ov = {v0, v1, v2, v3};
                *(float4*)(out + q * 768 + n * 192 + 4 * l) = ov;
            }
            break;
        }

        // agree = dot(hm row, v)
        if (act) {
            float4 vv = {v0, v1, v2, v3};
            *(float4*)&wbuf[w][4 * l] = vv;
        }
        float A = dotrow();
        a += p * A;

        // recursions: tq, D, tmean; fresh sy from registers
        t4x = (t4x + v0) * 0.5f; t4y = (t4y + v1) * 0.5f;
        t4z = (t4z + v2) * 0.5f; t4w = (t4w + v3) * 0.5f;
        float vmean = wave_sum((v0 + v1) + (v2 + v3)) * (1.0f / 192.0f);
        D = 0.5f * (D + A);
        tmean = 0.5f * (tmean + vmean);
        float t2s2 = wave_sum((t4x*t4x + t4y*t4y) + (t4z*t4z + t4w*t4w));
        sy = t2s2 - 192.0f * tmean * tmean;
        p = tanhf(-(D - tmean * S) * rsqrtf(sx_c * sy + EPSF));
    }
}

// ---------------- launch ----------------
extern "C" void kernel_launch(void* const* d_in, const int* in_sizes, int n_in,
                              void* d_out, int out_size, void* d_ws, size_t ws_size,
                              hipStream_t stream) {
    const float* m = (const float*)d_in[0];
    const float* q = (const float*)d_in[1];
    const float* W = (const float*)d_in[2];
    const float* b = (const float*)d_in[3];
    float* out = (float*)d_out;
    float* ws  = (float*)d_ws;

    const int Qn = in_sizes[1] / 768;      // 512

    float* hm = ws;                         // 4*64*192 = 49152 floats
    float* hq = ws + 49152;                 // Qn*768

    dim3 ggrid(18, 12);
    gemm_mq<<<ggrid, 256, 0, stream>>>(m, q, W, b, hm, hq);
    route_fused<<<Qn / 2, 512, 0, stream>>>(hm, hq, out);
}